// Round 1
// baseline (75.967 us; speedup 1.0000x reference)
//
#include <hip/hip_runtime.h>
#include <hip/hip_bf16.h>
#include <cstdint>

#define NN 2048
#define FF 64
#define BCC 16

typedef float f32x4 __attribute__((ext_vector_type(4)));
typedef __bf16 bf16x8 __attribute__((ext_vector_type(8)));

// ---------------- workspace layout (bytes) ----------------
// xT  : bf16[16][64][2048]  = 4,194,304   (off 0)
// U   : f32 [16][2048]      =   131,072   (off 4,194,304)   e^{f2}
// V   : f32 [16][2048]      =   131,072   (off 4,325,376)   e^{0.1 f2}
// F1  : f32 [16][2048]      =   131,072   (off 4,456,448)
// ADJ : u64 [2048][32]      =   524,288   (off 4,587,520)   bitmask
// total ~5.1 MB

// f1/f2 dot products + exp tables. One wave per (bc,n) row.
__global__ __launch_bounds__(256) void k_fvals(const float* __restrict__ x,
        const float* __restrict__ a1, const float* __restrict__ a2,
        float* __restrict__ U, float* __restrict__ V, float* __restrict__ F1) {
    int idx  = blockIdx.x * 4 + (threadIdx.x >> 6);   // bc*2048 + n
    int lane = threadIdx.x & 63;
    float xv = x[(size_t)idx * FF + lane];
    float d1 = xv * a1[lane];
    float d2 = xv * a2[lane];
    #pragma unroll
    for (int s = 32; s; s >>= 1) { d1 += __shfl_xor(d1, s); d2 += __shfl_xor(d2, s); }
    if (lane == 0) {
        F1[idx] = d1;
        U[idx]  = expf(d2);
        V[idx]  = expf(0.1f * d2);
    }
}

// pack adj -> bitmask via ballot. One wave per (row, 64-col chunk).
__global__ __launch_bounds__(256) void k_adj(const int* __restrict__ adj,
        unsigned long long* __restrict__ ADJ) {
    int idx  = blockIdx.x * 4 + (threadIdx.x >> 6);   // row*32 + chunk
    int lane = threadIdx.x & 63;
    int row = idx >> 5, chunk = idx & 31;
    int v = adj[(size_t)row * NN + chunk * 64 + lane];
    unsigned long long m = __ballot(v > 0);
    if (lane == 0) ADJ[(size_t)row * 32 + chunk] = m;
}

// transpose+cast x[bc][n][f] (f32) -> xT[bc][f][n] (bf16), 64x64 tiles
__global__ __launch_bounds__(256) void k_xt(const float* __restrict__ x,
        __hip_bfloat16* __restrict__ xT) {
    __shared__ float tile[64][65];
    int bc = blockIdx.x >> 5;
    int n0 = (blockIdx.x & 31) * 64;
    int tx = threadIdx.x & 63;
    int ty = threadIdx.x >> 6;
    const float* xp = x + ((size_t)bc * NN + n0) * FF;
    #pragma unroll
    for (int k = 0; k < 16; k++) {
        int nl = ty * 16 + k;
        tile[nl][tx] = xp[(size_t)nl * FF + tx];
    }
    __syncthreads();
    __hip_bfloat16* op = xT + (size_t)bc * FF * NN + n0;
    #pragma unroll
    for (int k = 0; k < 16; k++) {
        int fr = ty * 16 + k;
        op[(size_t)fr * NN + tx] = __float2bfloat16(tile[tx][fr]);
    }
}

// main: per block (bc, 64-row i-block). 4 waves: wid = it + 2*jh.
// wave handles 32 i-rows (2 MFMA A-tiles) x half the j range.
__global__ __launch_bounds__(256) void k_main(
        const __hip_bfloat16* __restrict__ xT, const float* __restrict__ U,
        const float* __restrict__ V, const float* __restrict__ F1,
        const unsigned long long* __restrict__ ADJ, float* __restrict__ out) {
    __shared__ float partial[2][32][65];
    __shared__ float zpart[2][32];
    __shared__ float ztot[2][32];

    int wid = threadIdx.x >> 6, lane = threadIdx.x & 63;
    int it = wid & 1, jh = wid >> 1;
    int bc   = blockIdx.x >> 5;
    int iblk = blockIdx.x & 31;
    int i0   = iblk * 64 + it * 32;
    int l15 = lane & 15, g = lane >> 4;

    const float* F1bc = F1 + bc * NN;
    float Ai[2], Bi[2], Ti[2];
    float zacc[2] = {0.f, 0.f};
    #pragma unroll
    for (int a = 0; a < 2; a++) {
        float f1 = F1bc[i0 + 16 * a + l15];
        Ai[a] = expf(f1);
        Bi[a] = expf(0.1f * f1);
        Ti[a] = expf(-f1);
    }

    f32x4 acc[2][4];
    #pragma unroll
    for (int a = 0; a < 2; a++)
        #pragma unroll
        for (int nb = 0; nb < 4; nb++)
            acc[a][nb] = (f32x4){0.f, 0.f, 0.f, 0.f};

    const float* Ubc = U + bc * NN;
    const float* Vbc = V + bc * NN;
    const __hip_bfloat16* xTbc = xT + (size_t)bc * FF * NN;
    const uint32_t* ADJ32 = (const uint32_t*)ADJ;   // [row][64] u32 words

    for (int jt = jh * 32; jt < jh * 32 + 32; jt++) {
        int jb = jt * 32 + 8 * g;                    // this lane's 8 j's
        f32x4 u0 = *(const f32x4*)(Ubc + jb);
        f32x4 u1 = *(const f32x4*)(Ubc + jb + 4);
        f32x4 v0 = *(const f32x4*)(Vbc + jb);
        f32x4 v1 = *(const f32x4*)(Vbc + jb + 4);
        bf16x8 bfrag[4];
        #pragma unroll
        for (int nb = 0; nb < 4; nb++)
            bfrag[nb] = *(const bf16x8*)(xTbc + (size_t)(nb * 16 + l15) * NN + jb);

        #pragma unroll
        for (int a = 0; a < 2; a++) {
            uint32_t w32 = ADJ32[(size_t)(i0 + 16 * a + l15) * 64 + jt];
            uint32_t m8 = (w32 >> (8 * g)) & 0xffu;
            bf16x8 af;
            float z = 0.f;
            #pragma unroll
            for (int t = 0; t < 8; t++) {
                float u = (t < 4) ? u0[t] : u1[t - 4];
                float v = (t < 4) ? v0[t] : v1[t - 4];
                float wgt = (u > Ti[a]) ? Ai[a] * u : Bi[a] * v;  // exp(lrelu(s))
                wgt = ((m8 >> t) & 1u) ? wgt : 0.f;               // adj mask
                z += wgt;
                af[t] = (__bf16)wgt;
            }
            zacc[a] += z;
            #pragma unroll
            for (int nb = 0; nb < 4; nb++)
                acc[a][nb] = __builtin_amdgcn_mfma_f32_16x16x32_bf16(
                    af, bfrag[nb], acc[a][nb], 0, 0, 0);
        }
    }

    // full row-sum Z within this wave's j-half (groups hold disjoint j)
    #pragma unroll
    for (int a = 0; a < 2; a++) {
        zacc[a] += __shfl_xor(zacc[a], 16);
        zacc[a] += __shfl_xor(zacc[a], 32);
    }

    // combine the two j-halves (waves jh=0 and jh=1 of the same it)
    if (jh == 1) {
        #pragma unroll
        for (int a = 0; a < 2; a++)
            #pragma unroll
            for (int nb = 0; nb < 4; nb++)
                #pragma unroll
                for (int r = 0; r < 4; r++) {
                    int il = 16 * a + g * 4 + r;      // D row = (l>>4)*4+reg
                    partial[it][il][nb * 16 + l15] = acc[a][nb][r];
                }
        if (lane < 16) {
            zpart[it][lane]      = zacc[0];
            zpart[it][16 + lane] = zacc[1];
        }
    }
    __syncthreads();
    if (jh == 0 && lane < 16) {
        ztot[it][lane]      = zacc[0] + zpart[it][lane];
        ztot[it][16 + lane] = zacc[1] + zpart[it][16 + lane];
    }
    __syncthreads();
    if (jh == 0) {
        float* outp = out + ((size_t)bc * NN + i0) * FF;
        #pragma unroll
        for (int a = 0; a < 2; a++)
            #pragma unroll
            for (int nb = 0; nb < 4; nb++)
                #pragma unroll
                for (int r = 0; r < 4; r++) {
                    int il = 16 * a + g * 4 + r;
                    int f  = nb * 16 + l15;
                    float val = acc[a][nb][r] + partial[it][il][f];
                    outp[(size_t)il * FF + f] = val / ztot[it][il];
                }
    }
}

extern "C" void kernel_launch(void* const* d_in, const int* in_sizes, int n_in,
                              void* d_out, int out_size, void* d_ws, size_t ws_size,
                              hipStream_t stream) {
    const float* x  = (const float*)d_in[0];
    const int* adj  = (const int*)d_in[1];
    const float* a1 = (const float*)d_in[2];
    const float* a2 = (const float*)d_in[3];
    float* out = (float*)d_out;

    char* ws = (char*)d_ws;
    __hip_bfloat16* xT = (__hip_bfloat16*)ws;
    float* U  = (float*)(ws + 4194304);
    float* V  = (float*)(ws + 4325376);
    float* F1 = (float*)(ws + 4456448);
    unsigned long long* ADJ = (unsigned long long*)(ws + 4587520);

    k_fvals<<<BCC * NN / 4, 256, 0, stream>>>(x, a1, a2, U, V, F1);
    k_adj  <<<NN * 32 / 4, 256, 0, stream>>>(adj, ADJ);
    k_xt   <<<BCC * 32, 256, 0, stream>>>(x, xT);
    k_main <<<BCC * 32, 256, 0, stream>>>(xT, U, V, F1, ADJ, out);
}

// Round 2
// 57.093 us; speedup vs baseline: 1.3306x; 1.3306x over previous
//
#include <hip/hip_runtime.h>
#include <hip/hip_bf16.h>
#include <cstdint>

#define NN 2048
#define FF 64
#define BCC 16

typedef float f32x4 __attribute__((ext_vector_type(4)));
typedef __bf16 bf16x8 __attribute__((ext_vector_type(8)));
typedef uint32_t u32x4 __attribute__((ext_vector_type(4)));

// ---------------- workspace layout (bytes) ----------------
// xT  : bf16[16][64][2048]  = 4,194,304   (off 0)
// U   : f32 [16][2048]      =   131,072   (off 4,194,304)   e^{f2}
// V   : f32 [16][2048]      =   131,072   (off 4,325,376)   e^{0.1 f2}
// CI  : f32 [16][2048]      =   131,072   (off 4,456,448)   e^{-0.9 f1}
// ADJ : u64 [2048][32]      =   524,288   (off 4,587,520)   bitmask
// total ~5.1 MB

// fused: transpose+cast x -> xT, plus per-row dots f1,f2 -> CI,U,V tables.
__global__ __launch_bounds__(256) void k_prep(const float* __restrict__ x,
        const float* __restrict__ a1, const float* __restrict__ a2,
        __hip_bfloat16* __restrict__ xT, float* __restrict__ U,
        float* __restrict__ V, float* __restrict__ CI) {
    __shared__ float tile[64][65];
    __shared__ float red[2][64][4];
    int bc = blockIdx.x >> 5;
    int n0 = (blockIdx.x & 31) * 64;
    int tx = threadIdx.x & 63;
    int ty = threadIdx.x >> 6;
    const float* xp = x + ((size_t)bc * NN + n0) * FF;
    #pragma unroll
    for (int k = 0; k < 16; k++) {
        int nl = ty * 16 + k;
        tile[nl][tx] = xp[(size_t)nl * FF + tx];
    }
    __syncthreads();
    // transpose+cast write
    __hip_bfloat16* op = xT + (size_t)bc * FF * NN + n0;
    #pragma unroll
    for (int k = 0; k < 16; k++) {
        int fr = ty * 16 + k;
        op[(size_t)fr * NN + tx] = __float2bfloat16(tile[tx][fr]);
    }
    // dots: thread handles row tx, f-quarter ty
    float d1 = 0.f, d2 = 0.f;
    #pragma unroll
    for (int i = 0; i < 16; i++) {
        int f = ty * 16 + i;
        float xv = tile[tx][f];
        d1 += xv * a1[f];
        d2 += xv * a2[f];
    }
    red[0][tx][ty] = d1;
    red[1][tx][ty] = d2;
    __syncthreads();
    if (ty == 0) {
        float f1 = red[0][tx][0] + red[0][tx][1] + red[0][tx][2] + red[0][tx][3];
        float f2 = red[1][tx][0] + red[1][tx][1] + red[1][tx][2] + red[1][tx][3];
        int idx = bc * NN + n0 + tx;
        U[idx]  = expf(f2);
        V[idx]  = expf(0.1f * f2);
        CI[idx] = expf(-0.9f * f1);
    }
}

// pack adj -> bitmask via ballot. One wave per (row, 4x 64-col chunks).
__global__ __launch_bounds__(256) void k_adj(const int* __restrict__ adj,
        unsigned long long* __restrict__ ADJ) {
    int idx  = blockIdx.x * 4 + (threadIdx.x >> 6);   // row*8 + cg
    int lane = threadIdx.x & 63;
    int row = idx >> 3, cg = idx & 7;
    const int* p = adj + (size_t)row * NN + cg * 256 + lane;
    unsigned long long m0 = __ballot(p[0]   > 0);
    unsigned long long m1 = __ballot(p[64]  > 0);
    unsigned long long m2 = __ballot(p[128] > 0);
    unsigned long long m3 = __ballot(p[192] > 0);
    if (lane == 0) {
        unsigned long long* q = ADJ + (size_t)row * 32 + cg * 4;
        q[0] = m0; q[1] = m1; q[2] = m2; q[3] = m3;
    }
}

// main: block = (bc, 32-row i-block); 4 waves, wave jq owns j-quarter (512 j).
// weights w' = adj * max(u_j, Ci*v_j)  (softmax row-scale invariance).
__global__ __launch_bounds__(256) void k_main(
        const __hip_bfloat16* __restrict__ xT, const float* __restrict__ U,
        const float* __restrict__ V, const float* __restrict__ CI,
        const unsigned long long* __restrict__ ADJ, float* __restrict__ out) {
    __shared__ float partial[3][32][66];
    __shared__ float zpart[3][32];
    __shared__ float zfull[32];

    int jq = threadIdx.x >> 6, lane = threadIdx.x & 63;
    // XCD swizzle: 1024 blocks -> 128 contiguous logical ids per XCD
    int bid  = ((blockIdx.x & 7) << 7) | (blockIdx.x >> 3);
    int bc   = bid >> 6;
    int iblk = bid & 63;
    int i0   = iblk * 32;
    int l15 = lane & 15, g = lane >> 4;

    float Ci[2];
    Ci[0] = CI[bc * NN + i0 + l15];
    Ci[1] = CI[bc * NN + i0 + 16 + l15];

    f32x4 acc[2][4];
    #pragma unroll
    for (int a = 0; a < 2; a++)
        #pragma unroll
        for (int nb = 0; nb < 4; nb++)
            acc[a][nb] = (f32x4){0.f, 0.f, 0.f, 0.f};
    float zacc[2] = {0.f, 0.f};

    const float* Ubc = U + bc * NN;
    const float* Vbc = V + bc * NN;
    const __hip_bfloat16* xTbc = xT + (size_t)bc * FF * NN;
    const uint32_t* ADJ32 = (const uint32_t*)ADJ;   // [row][64] u32 words

    for (int jt4 = 0; jt4 < 4; jt4++) {
        int jtbase = jq * 16 + jt4 * 4;
        u32x4 aw[2];
        aw[0] = *(const u32x4*)(ADJ32 + (size_t)(i0 + l15) * 64 + jtbase);
        aw[1] = *(const u32x4*)(ADJ32 + (size_t)(i0 + 16 + l15) * 64 + jtbase);
        #pragma unroll
        for (int jj = 0; jj < 4; jj++) {
            int jt = jtbase + jj;
            int jb = jt * 32 + 8 * g;                // this lane's 8 j's
            f32x4 u0 = *(const f32x4*)(Ubc + jb);
            f32x4 u1 = *(const f32x4*)(Ubc + jb + 4);
            f32x4 v0 = *(const f32x4*)(Vbc + jb);
            f32x4 v1 = *(const f32x4*)(Vbc + jb + 4);
            bf16x8 bfrag[4];
            #pragma unroll
            for (int nb = 0; nb < 4; nb++)
                bfrag[nb] = *(const bf16x8*)(xTbc + (size_t)(nb * 16 + l15) * NN + jb);

            #pragma unroll
            for (int a = 0; a < 2; a++) {
                uint32_t m8 = (aw[a][jj] >> (8 * g)) & 0xffu;
                bf16x8 af;
                float z = 0.f;
                #pragma unroll
                for (int t = 0; t < 8; t++) {
                    float uu = (t < 4) ? u0[t] : u1[t - 4];
                    float vv = (t < 4) ? v0[t] : v1[t - 4];
                    float m  = fmaxf(uu, Ci[a] * vv);    // exp(lrelu)/e^{f1}
                    float w  = ((m8 >> t) & 1u) ? m : 0.f;
                    z += w;
                    af[t] = (__bf16)w;
                }
                zacc[a] += z;
                #pragma unroll
                for (int nb = 0; nb < 4; nb++)
                    acc[a][nb] = __builtin_amdgcn_mfma_f32_16x16x32_bf16(
                        af, bfrag[nb], acc[a][nb], 0, 0, 0);
            }
        }
    }

    // full row-sum Z within this wave's j-quarter (groups hold disjoint j)
    #pragma unroll
    for (int a = 0; a < 2; a++) {
        zacc[a] += __shfl_xor(zacc[a], 16);
        zacc[a] += __shfl_xor(zacc[a], 32);
    }

    if (jq > 0) {
        #pragma unroll
        for (int a = 0; a < 2; a++)
            #pragma unroll
            for (int nb = 0; nb < 4; nb++)
                #pragma unroll
                for (int r = 0; r < 4; r++) {
                    int il = 16 * a + g * 4 + r;      // D row = (l>>4)*4+reg
                    partial[jq - 1][il][nb * 16 + l15] = acc[a][nb][r];
                }
        if (lane < 16) {
            zpart[jq - 1][lane]      = zacc[0];
            zpart[jq - 1][16 + lane] = zacc[1];
        }
    }
    __syncthreads();
    if (jq == 0) {
        if (g == 0) {
            zfull[l15]      = zacc[0] + zpart[0][l15] + zpart[1][l15] + zpart[2][l15];
            zfull[16 + l15] = zacc[1] + zpart[0][16 + l15] + zpart[1][16 + l15] + zpart[2][16 + l15];
        }
        float zinv[2][4];
        #pragma unroll
        for (int a = 0; a < 2; a++)
            #pragma unroll
            for (int r = 0; r < 4; r++)
                zinv[a][r] = 1.0f / zfull[16 * a + g * 4 + r];
        float* outp = out + ((size_t)bc * NN + i0) * FF;
        #pragma unroll
        for (int a = 0; a < 2; a++)
            #pragma unroll
            for (int nb = 0; nb < 4; nb++)
                #pragma unroll
                for (int r = 0; r < 4; r++) {
                    int il = 16 * a + g * 4 + r;
                    int f  = nb * 16 + l15;
                    float val = acc[a][nb][r] + partial[0][il][f] + partial[1][il][f]
                              + partial[2][il][f];
                    outp[(size_t)il * FF + f] = val * zinv[a][r];
                }
    }
}

extern "C" void kernel_launch(void* const* d_in, const int* in_sizes, int n_in,
                              void* d_out, int out_size, void* d_ws, size_t ws_size,
                              hipStream_t stream) {
    const float* x  = (const float*)d_in[0];
    const int* adj  = (const int*)d_in[1];
    const float* a1 = (const float*)d_in[2];
    const float* a2 = (const float*)d_in[3];
    float* out = (float*)d_out;

    char* ws = (char*)d_ws;
    __hip_bfloat16* xT = (__hip_bfloat16*)ws;
    float* U  = (float*)(ws + 4194304);
    float* V  = (float*)(ws + 4325376);
    float* CI = (float*)(ws + 4456448);
    unsigned long long* ADJ = (unsigned long long*)(ws + 4587520);

    k_prep<<<BCC * 32, 256, 0, stream>>>(x, a1, a2, xT, U, V, CI);
    k_adj <<<NN * 8 / 4, 256, 0, stream>>>(adj, ADJ);
    k_main<<<BCC * 64, 256, 0, stream>>>(xT, U, V, CI, ADJ, out);
}

// Round 3
// 34.538 us; speedup vs baseline: 2.1996x; 1.6531x over previous
//
#include <hip/hip_runtime.h>
#include <hip/hip_bf16.h>
#include <cstdint>

#define NN 2048
#define FF 64
#define BCC 16

typedef float f32x4 __attribute__((ext_vector_type(4)));
typedef __bf16 bf16x8 __attribute__((ext_vector_type(8)));

// ---------------- workspace layout (bytes) ----------------
// xP   : bf16 packed [16][jt=64][nb=4][lane=64][e=8] = 4,194,304  (off 0)
//        element (bc,jt,nb,(g,l15),e) = x[bc][n = jt*32+8g+e][f = nb*16+l15]
// U    : f32 [16][2048] = 131,072  (off 4,194,304)   e^{f2}
// V    : f32 [16][2048] = 131,072  (off 4,325,376)   e^{0.1 f2}
// CI   : f32 [16][2048] = 131,072  (off 4,456,448)   e^{-0.9 f1}
// ADJB : u8  [bj=256][row=2048] = 524,288 (off 4,587,520)  bj = j/8 bitmask byte
// total ~5.1 MB

// fused prep: blocks [0,512): transpose/pack x + per-row dot/exp tables.
//             blocks [512,4608): adj -> transposed byte bitmask.
__global__ __launch_bounds__(256) void k_prep(const float* __restrict__ x,
        const int* __restrict__ adj,
        const float* __restrict__ a1, const float* __restrict__ a2,
        __hip_bfloat16* __restrict__ xP, float* __restrict__ U,
        float* __restrict__ V, float* __restrict__ CI,
        unsigned char* __restrict__ ADJB) {
    int wid  = threadIdx.x >> 6;
    int lane = threadIdx.x & 63;

    if (blockIdx.x >= 512) {                 // ---- adj packing ----
        int idx = (blockIdx.x - 512) * 4 + wid;   // row*8 + cg
        int row = idx >> 3, cg = idx & 7;
        const int* p = adj + (size_t)row * NN + cg * 256 + lane;
        unsigned long long m0 = __ballot(p[0]   > 0);
        unsigned long long m1 = __ballot(p[64]  > 0);
        unsigned long long m2 = __ballot(p[128] > 0);
        unsigned long long m3 = __ballot(p[192] > 0);
        if (lane < 32) {
            unsigned long long m = (lane < 8) ? m0 : (lane < 16) ? m1
                                 : (lane < 24) ? m2 : m3;
            unsigned char byte = (unsigned char)(m >> (8 * (lane & 7)));
            ADJB[(size_t)(cg * 32 + lane) * NN + row] = byte;
        }
        return;
    }

    // ---- x pack + tables ----
    __shared__ float tile[64][65];
    __shared__ float red[2][64][4];
    int bc = blockIdx.x >> 5;
    int n0 = (blockIdx.x & 31) * 64;
    int tx = lane;
    int ty = wid;
    const float* xp = x + ((size_t)bc * NN + n0) * FF;
    #pragma unroll
    for (int k = 0; k < 16; k++) {
        int nl = ty * 16 + k;
        tile[nl][tx] = xp[(size_t)nl * FF + tx];
    }
    __syncthreads();
    // packed fragment-order write (coalesced 16B per lane)
    int g = lane >> 4, l15 = lane & 15;
    int jt0 = n0 >> 5;
    #pragma unroll
    for (int jl = 0; jl < 2; jl++) {
        bf16x8 val;
        #pragma unroll
        for (int e = 0; e < 8; e++)
            val[e] = (__bf16)tile[jl * 32 + 8 * g + e][ty * 16 + l15];
        ((bf16x8*)xP)[(((size_t)bc * 64 + jt0 + jl) * 4 + ty) * 64 + lane] = val;
    }
    // dots: thread handles row tx, f-quarter ty
    float d1 = 0.f, d2 = 0.f;
    #pragma unroll
    for (int i = 0; i < 16; i++) {
        int f = ty * 16 + i;
        float xv = tile[tx][f];
        d1 += xv * a1[f];
        d2 += xv * a2[f];
    }
    red[0][tx][ty] = d1;
    red[1][tx][ty] = d2;
    __syncthreads();
    if (ty == 0) {
        float f1 = red[0][tx][0] + red[0][tx][1] + red[0][tx][2] + red[0][tx][3];
        float f2 = red[1][tx][0] + red[1][tx][1] + red[1][tx][2] + red[1][tx][3];
        int idx = bc * NN + n0 + tx;
        U[idx]  = expf(f2);
        V[idx]  = expf(0.1f * f2);
        CI[idx] = expf(-0.9f * f1);
    }
}

// main: block = (bc, 32-row i-block); 4 waves, wave jq owns j-quarter (512 j).
// weights w' = adj * max(u_j, Ci*v_j)  (softmax row-scale invariance).
__global__ __launch_bounds__(256) void k_main(
        const __hip_bfloat16* __restrict__ xP, const float* __restrict__ U,
        const float* __restrict__ V, const float* __restrict__ CI,
        const unsigned char* __restrict__ ADJB, float* __restrict__ out) {
    __shared__ float partial[3][32][66];
    __shared__ float zpart[3][32];
    __shared__ float zfull[32];

    int jq = threadIdx.x >> 6, lane = threadIdx.x & 63;
    // XCD swizzle: 1024 blocks -> 128 contiguous logical ids per XCD
    int bid  = ((blockIdx.x & 7) << 7) | (blockIdx.x >> 3);
    int bc   = bid >> 6;
    int iblk = bid & 63;
    int i0   = iblk * 32;
    int l15 = lane & 15, g = lane >> 4;

    float Ci[2];
    Ci[0] = CI[bc * NN + i0 + l15];
    Ci[1] = CI[bc * NN + i0 + 16 + l15];

    f32x4 acc[2][4];
    #pragma unroll
    for (int a = 0; a < 2; a++)
        #pragma unroll
        for (int nb = 0; nb < 4; nb++)
            acc[a][nb] = (f32x4){0.f, 0.f, 0.f, 0.f};
    float zacc[2] = {0.f, 0.f};

    const float* Ubc = U + bc * NN;
    const float* Vbc = V + bc * NN;
    const bf16x8* xPbc = (const bf16x8*)xP + (size_t)bc * 16384;

    for (int jtb = 0; jtb < 4; jtb++) {
        #pragma unroll
        for (int jj = 0; jj < 4; jj++) {
            int jt = jq * 16 + jtb * 4 + jj;
            // coalesced fragment loads: base + lane*16B, imm offsets for nb
            const bf16x8* xpw = xPbc + (size_t)jt * 256 + lane;
            bf16x8 bf0 = xpw[0], bf1 = xpw[64], bf2 = xpw[128], bf3 = xpw[192];
            const f32x4* up = (const f32x4*)Ubc + jt * 8 + 2 * g;
            const f32x4* vp = (const f32x4*)Vbc + jt * 8 + 2 * g;
            f32x4 u0 = up[0], u1 = up[1];
            f32x4 v0 = vp[0], v1 = vp[1];
            const unsigned char* ap = ADJB + ((size_t)(jt * 4 + g) << 11) + i0 + l15;
            uint32_t m8[2];
            m8[0] = ap[0];
            m8[1] = ap[16];

            #pragma unroll
            for (int a = 0; a < 2; a++) {
                bf16x8 af;
                float z = 0.f;
                #pragma unroll
                for (int t = 0; t < 8; t++) {
                    float uu = (t < 4) ? u0[t] : u1[t - 4];
                    float vv = (t < 4) ? v0[t] : v1[t - 4];
                    float m  = fmaxf(uu, Ci[a] * vv);    // exp(lrelu)/e^{f1}
                    float w  = ((m8[a] >> t) & 1u) ? m : 0.f;
                    z += w;
                    af[t] = (__bf16)w;
                }
                zacc[a] += z;
                acc[a][0] = __builtin_amdgcn_mfma_f32_16x16x32_bf16(af, bf0, acc[a][0], 0, 0, 0);
                acc[a][1] = __builtin_amdgcn_mfma_f32_16x16x32_bf16(af, bf1, acc[a][1], 0, 0, 0);
                acc[a][2] = __builtin_amdgcn_mfma_f32_16x16x32_bf16(af, bf2, acc[a][2], 0, 0, 0);
                acc[a][3] = __builtin_amdgcn_mfma_f32_16x16x32_bf16(af, bf3, acc[a][3], 0, 0, 0);
            }
        }
    }

    // full row-sum Z within this wave's j-quarter (groups hold disjoint j)
    #pragma unroll
    for (int a = 0; a < 2; a++) {
        zacc[a] += __shfl_xor(zacc[a], 16);
        zacc[a] += __shfl_xor(zacc[a], 32);
    }

    if (jq > 0) {
        #pragma unroll
        for (int a = 0; a < 2; a++)
            #pragma unroll
            for (int nb = 0; nb < 4; nb++)
                #pragma unroll
                for (int r = 0; r < 4; r++) {
                    int il = 16 * a + g * 4 + r;      // D row = (l>>4)*4+reg
                    partial[jq - 1][il][nb * 16 + l15] = acc[a][nb][r];
                }
        if (lane < 16) {
            zpart[jq - 1][lane]      = zacc[0];
            zpart[jq - 1][16 + lane] = zacc[1];
        }
    }
    __syncthreads();
    if (jq == 0) {
        if (g == 0) {
            zfull[l15]      = zacc[0] + zpart[0][l15] + zpart[1][l15] + zpart[2][l15];
            zfull[16 + l15] = zacc[1] + zpart[0][16 + l15] + zpart[1][16 + l15] + zpart[2][16 + l15];
        }
        float zinv[2][4];
        #pragma unroll
        for (int a = 0; a < 2; a++)
            #pragma unroll
            for (int r = 0; r < 4; r++)
                zinv[a][r] = 1.0f / zfull[16 * a + g * 4 + r];
        float* outp = out + ((size_t)bc * NN + i0) * FF;
        #pragma unroll
        for (int a = 0; a < 2; a++)
            #pragma unroll
            for (int nb = 0; nb < 4; nb++)
                #pragma unroll
                for (int r = 0; r < 4; r++) {
                    int il = 16 * a + g * 4 + r;
                    int f  = nb * 16 + l15;
                    float val = acc[a][nb][r] + partial[0][il][f] + partial[1][il][f]
                              + partial[2][il][f];
                    outp[(size_t)il * FF + f] = val * zinv[a][r];
                }
    }
}

extern "C" void kernel_launch(void* const* d_in, const int* in_sizes, int n_in,
                              void* d_out, int out_size, void* d_ws, size_t ws_size,
                              hipStream_t stream) {
    const float* x  = (const float*)d_in[0];
    const int* adj  = (const int*)d_in[1];
    const float* a1 = (const float*)d_in[2];
    const float* a2 = (const float*)d_in[3];
    float* out = (float*)d_out;

    char* ws = (char*)d_ws;
    __hip_bfloat16* xP = (__hip_bfloat16*)ws;
    float* U  = (float*)(ws + 4194304);
    float* V  = (float*)(ws + 4325376);
    float* CI = (float*)(ws + 4456448);
    unsigned char* ADJB = (unsigned char*)(ws + 4587520);

    k_prep<<<512 + 4096, 256, 0, stream>>>(x, adj, a1, a2, xP, U, V, CI, ADJB);
    k_main<<<BCC * 64, 256, 0, stream>>>(xP, U, V, CI, ADJB, out);
}